// Round 3
// baseline (4001.369 us; speedup 1.0000x reference)
//
#include <hip/hip_runtime.h>
#include <hip/hip_bf16.h>
#include <cstdint>
#include <cstddef>

// Problem dims
constexpr int Bz = 128, Tz = 25, Ez = 512, Hz = 1024, Vz = 10000, Fz = 2048;

typedef unsigned short u16;
typedef __attribute__((ext_vector_type(8))) short bf16x8;   // 8 bf16 (4 VGPRs)
typedef __attribute__((ext_vector_type(4))) float f32x4;    // 4 f32 acc

__device__ __forceinline__ float sigm(float x) { return 1.f / (1.f + __expf(-x)); }
__device__ __forceinline__ float tanh_f(float x) {
    float e = __expf(-2.f * x);
    return 2.f / (1.f + e) - 1.f;
}
__device__ __forceinline__ float bf2f(u16 u) {
    return __builtin_bit_cast(float, ((unsigned)u) << 16);
}
__device__ __forceinline__ u16 f2bf(float x) {   // RNE
    unsigned u = __builtin_bit_cast(unsigned, x);
    u += 0x7fffu + ((u >> 16) & 1u);
    return (u16)(u >> 16);
}
__device__ __forceinline__ void splitbf(float x, u16& h, u16& l) {
    h = f2bf(x);
    l = f2bf(x - bf2f(h));
}

// ---------------- dtype detector (bf16=1 / f32=0), from embedding halfwords ----
__global__ __launch_bounds__(256) void detect_k(const u16* __restrict__ raw,
                                                int* __restrict__ flag) {
    __shared__ int sbuf[256];
    int tid = threadIdx.x, cnt = 0;
    for (int i = tid; i < 1024; i += 256) {
        u16 u = raw[2 * i];
        int e = (u >> 7) & 0xff;
        if (e >= 110 && e <= 127) cnt++;
    }
    sbuf[tid] = cnt;
    __syncthreads();
    for (int s = 128; s > 0; s >>= 1) {
        if (tid < s) sbuf[tid] += sbuf[tid + s];
        __syncthreads();
    }
    if (tid == 0) flag[0] = (sbuf[0] >= 512) ? 1 : 0;
}

__device__ __forceinline__ float ldf(const void* p, size_t i, int isbf) {
    return isbf ? bf2f(((const u16*)p)[i]) : ((const float*)p)[i];
}

// ---------------- embedding gather -> f32 X0 (f32 fallback only) ----------------
__global__ __launch_bounds__(256) void gatherf_k(const int* __restrict__ tok,
                                                 const void* __restrict__ emb,
                                                 float* __restrict__ X0,
                                                 const int* __restrict__ flag) {
    if (*flag) return;   // bf16 path gathers inside the MFMA GEMM
    int idx = blockIdx.x * 256 + threadIdx.x;
    if (idx >= 3200 * (Ez / 4)) return;
    int r = idx >> 7, c4 = (idx & 127) << 2;
    int t = r >> 7, b = r & 127;
    int tk = tok[b * Tz + t];
    float4 o;
    o.x = ldf(emb, (size_t)tk * Ez + c4 + 0, 0);
    o.y = ldf(emb, (size_t)tk * Ez + c4 + 1, 0);
    o.z = ldf(emb, (size_t)tk * Ez + c4 + 2, 0);
    o.w = ldf(emb, (size_t)tk * Ez + c4 + 3, 0);
    *(float4*)(X0 + (size_t)r * Ez + c4) = o;
}

// ---------------- features -> f32 ----------------
__global__ __launch_bounds__(256) void convf_k(const void* __restrict__ in,
                                               float* __restrict__ out, int n,
                                               const int* __restrict__ flag) {
    int idx = blockIdx.x * 256 + threadIdx.x;
    if (idx >= n) return;
    out[idx] = ldf(in, idx, *flag);
}

// ---------------- bias pack to f32 ----------------
__global__ __launch_bounds__(256) void pack2_k(
    const void* __restrict__ bp,
    const void* __restrict__ bf0, const void* __restrict__ bi0,
    const void* __restrict__ bo0, const void* __restrict__ bg0,
    const void* __restrict__ bf1, const void* __restrict__ bi1,
    const void* __restrict__ bo1, const void* __restrict__ bg1,
    const void* __restrict__ bout,
    float* __restrict__ bp_f, float* __restrict__ b0_f, float* __restrict__ b1_f,
    float* __restrict__ bout_f, const int* __restrict__ flag) {
    int idx = blockIdx.x * 256 + threadIdx.x;
    int isbf = *flag;
    if (idx < 1024) {
        bp_f[idx] = ldf(bp, idx, isbf);
    } else if (idx < 5120) {
        int n = idx - 1024, g = n >> 10, j = n & 1023;
        const void* s = (g == 0) ? bf0 : (g == 1) ? bi0 : (g == 2) ? bo0 : bg0;
        b0_f[n] = ldf(s, j, isbf);
    } else if (idx < 9216) {
        int n = idx - 5120, g = n >> 10, j = n & 1023;
        const void* s = (g == 0) ? bf1 : (g == 1) ? bi1 : (g == 2) ? bo1 : bg1;
        b1_f[n] = ldf(s, j, isbf);
    } else if (idx < 9216 + Vz) {
        int n = idx - 9216;
        bout_f[n] = ldf(bout, n, isbf);
    }
}

// ---------------- weight transpose W[K][N] bf16 -> Wt[z*N + n][K] (bf16 only) ---
__global__ __launch_bounds__(256) void trans_k(
    const u16* __restrict__ s0, const u16* __restrict__ s1,
    const u16* __restrict__ s2, const u16* __restrict__ s3,
    int K, int N, u16* __restrict__ dst, const int* __restrict__ flag) {
    if (!*flag) return;
    const u16* src = (blockIdx.z == 0) ? s0 : (blockIdx.z == 1) ? s1
                   : (blockIdx.z == 2) ? s2 : s3;
    __shared__ u16 tb[32][33];
    int n0 = blockIdx.x * 32, k0 = blockIdx.y * 32, tid = threadIdx.x;
    for (int i = 0; i < 4; i++) {
        int idx = i * 256 + tid, rr = idx >> 5, cc = idx & 31;
        int k = k0 + rr, n = n0 + cc;
        tb[rr][cc] = (n < N) ? src[(size_t)k * N + n] : (u16)0;
    }
    __syncthreads();
    size_t dbase = (size_t)blockIdx.z * N;
    for (int i = 0; i < 4; i++) {
        int idx = i * 256 + tid, rr = idx >> 5, cc = idx & 31;
        int n = n0 + rr, k = k0 + cc;
        if (n < N) dst[(dbase + n) * K + k] = tb[cc][rr];
    }
}

// ---------------- LSTM cell elementwise, fused partial-sum (P=4) ----------------
__global__ __launch_bounds__(256) void cellu_k(
    const float* __restrict__ parts, const float* __restrict__ add,
    int astride, int amask, float* __restrict__ c,
    u16* __restrict__ hi1, u16* __restrict__ lo1, float* __restrict__ f1, int ld1,
    u16* __restrict__ hi2, u16* __restrict__ lo2, float* __restrict__ f2, int ld2,
    const int* __restrict__ flag) {
    int idx = blockIdx.x * 256 + threadIdx.x;   // 131072
    int m = idx >> 10, j = idx & 1023;
    size_t ab = (size_t)(m & amask) * astride;
    float gf = add[ab + j];
    float gi = add[ab + 1024 + j];
    float go = add[ab + 2048 + j];
    float gg = add[ab + 3072 + j];
    size_t base = (size_t)m * 4096 + j;
#pragma unroll
    for (int p = 0; p < 4; ++p) {
        const float* pp = parts + (size_t)p * 524288 + base;
        gf += pp[0]; gi += pp[1024]; go += pp[2048]; gg += pp[3072];
    }
    float f = sigm(gf), ii = sigm(gi), o = sigm(go), g = tanh_f(gg);
    float cn = f * c[idx] + ii * g;
    c[idx] = cn;
    float h = o * tanh_f(cn);
    u16 hh, hl;
    splitbf(h, hh, hl);
    size_t o1 = (size_t)m * ld1 + j, o2 = (size_t)m * ld2 + j;
    hi1[o1] = hh; lo1[o1] = hl;
    hi2[o2] = hh; lo2[o2] = hl;
    if (!*flag) { f1[o1] = h; f2[o2] = h; }   // f32 copies only for fallback (aliased ws!)
}

// ---------------- partial-sum reducer (+bias, leaky, optional bf16 split) -------
template <int ACT, int SPLIT>
__global__ __launch_bounds__(256) void sumPu_k(
    const float* __restrict__ parts, int Ns, const float* __restrict__ addv,
    int astride, int amask, float* __restrict__ out,
    u16* __restrict__ ohi, u16* __restrict__ olo, int total) {
    int idx = blockIdx.x * 256 + threadIdx.x;
    if (idx >= total) return;
    int m = idx >> Ns, col = idx & ((1 << Ns) - 1);
    float v = addv[(size_t)(m & amask) * astride + col];
#pragma unroll
    for (int p = 0; p < 4; ++p) v += parts[(size_t)p * total + idx];
    if (ACT == 1) v = (v > 0.f) ? v : 0.01f * v;
    out[idx] = v;
    if (SPLIT) {
        u16 hh, hl;
        splitbf(v, hh, hl);
        ohi[idx] = hh; olo[idx] = hl;
    }
}

// =============================================================================
// VALU f32 GEMM (feat projection: both dtypes; and general f32 fallback pieces)
// C partial = A[128,K-chunk] @ B(orig layout) -> Cpart[z][128][N]
// =============================================================================
template <bool MULTI>
__global__ __launch_bounds__(256) void sgemm_part_k(
    const float* __restrict__ A, int lda,
    const void* __restrict__ B0, const void* __restrict__ B1,
    const void* __restrict__ B2, const void* __restrict__ B3,
    int ldb, int rowoff,
    float* __restrict__ Cpart, int N, int KC,
    const int* __restrict__ flag) {
    __shared__ float As[16][68];
    __shared__ float Bs[16][68];
    const int tid = threadIdx.x;
    const int tx = tid & 15, ty = tid >> 4;
    const int bn0 = blockIdx.x * 64, bm0 = blockIdx.y * 64;
    const int kbase = blockIdx.z * KC;
    const int isbf = *flag;
    const int ar = tid >> 2, ac4 = (tid & 3) << 2;
    const int bkk = tid >> 4, bn4 = (tid & 15) << 2;

    float acc[4][4];
#pragma unroll
    for (int i = 0; i < 4; i++)
#pragma unroll
        for (int j = 0; j < 4; j++) acc[i][j] = 0.f;

    float4 pa, pb;
    auto loadA = [&](int kt) {
        pa = *(const float4*)(A + (size_t)(bm0 + ar) * lda + kbase + kt + ac4);
    };
    auto loadB = [&](int kt) {
        int ng = bn0 + bn4;
        const void* bptr; int col;
        if constexpr (MULTI) {
            int pi = ng >> 10;
            bptr = (pi == 0) ? B0 : (pi == 1) ? B1 : (pi == 2) ? B2 : B3;
            col = ng & 1023;
        } else { bptr = B0; col = ng; }
        size_t off = (size_t)(rowoff + kbase + kt + bkk) * ldb + col;
        if (isbf) {
            const u16* us = (const u16*)bptr + off;
            pb.x = bf2f(us[0]); pb.y = bf2f(us[1]);
            pb.z = bf2f(us[2]); pb.w = bf2f(us[3]);
        } else {
            pb = *(const float4*)((const float*)bptr + off);
        }
    };

    loadA(0); loadB(0);
    for (int kt = 0; kt < KC; kt += 16) {
        As[ac4 + 0][ar] = pa.x; As[ac4 + 1][ar] = pa.y;
        As[ac4 + 2][ar] = pa.z; As[ac4 + 3][ar] = pa.w;
        *(float4*)&Bs[bkk][bn4] = pb;
        __syncthreads();
        if (kt + 16 < KC) { loadA(kt + 16); loadB(kt + 16); }
#pragma unroll
        for (int kk = 0; kk < 16; ++kk) {
            float a[4], b[4];
            *(float4*)&a[0] = *(const float4*)&As[kk][ty * 4];
            *(float4*)&b[0] = *(const float4*)&Bs[kk][tx * 4];
#pragma unroll
            for (int i = 0; i < 4; ++i)
#pragma unroll
                for (int j = 0; j < 4; ++j)
                    acc[i][j] = fmaf(a[i], b[j], acc[i][j]);
        }
        __syncthreads();
    }
    float* out = Cpart + (size_t)blockIdx.z * 128 * N;
#pragma unroll
    for (int i = 0; i < 4; ++i)
#pragma unroll
        for (int j = 0; j < 4; ++j)
            out[(size_t)(bm0 + ty * 4 + i) * N + bn0 + tx * 4 + j] = acc[i][j];
}

// =============================================================================
// Unified recurrent GEMM -> parts[z][128][4096].
//   MFMA path (isbf): 128x256 macro-tile, BK=32, bf16 hi/lo A-split, Bt=[4096][K]
//     A = concat( x_t from embedding (XMODE, k<kspl, exact bf16) , h hi/lo )
//     B col = kg (+hoff for k>=kspl).  Grid uses linear blocks 0..63 (16n x 4z).
//   VALU path (!isbf): f32 fallback, old 64x64 split-K, orig weight layout.
// Launched as dim3(64,2,4).
// =============================================================================
template <int XMODE>
__global__ __launch_bounds__(256, 2) void rgemm_k(
    const int* __restrict__ flag, int t,
    const int* __restrict__ tokens, const u16* __restrict__ emb,
    const u16* __restrict__ Ah_hi, const u16* __restrict__ Ah_lo, int ldah,
    int kspl, int hoff,
    const u16* __restrict__ Bt, int ldbt,
    int KCm,
    float* __restrict__ parts,
    const float* __restrict__ Axf, const float* __restrict__ Ahf, int ldahf,
    const void* __restrict__ B0, const void* __restrict__ B1,
    const void* __restrict__ B2, const void* __restrict__ B3, int ldb, int KCv) {
    __shared__ int4 shraw[2560];   // 40960 B, shared by both paths
    const int tid = threadIdx.x;
    const int isbf = *flag;
    if (isbf) {
        // ---------------- MFMA path ----------------
        int lid = (blockIdx.z * 2 + blockIdx.y) * 64 + blockIdx.x;
        if (lid >= 64) return;
        const int bn0 = (lid & 15) * 256;
        const int z = lid >> 4;
        const int kbase = z * KCm;
        u16* Ahi = (u16*)shraw;          // [128][40]
        u16* Alo = Ahi + 128 * 40;       // [128][40]
        u16* Bsh = Alo + 128 * 40;       // [256][40]
        const int wid = tid >> 6, lane = tid & 63;
        const int l15 = lane & 15, g = lane >> 4;
        const int wr0 = (wid >> 1) * 64, wc0 = (wid & 1) * 128;

        f32x4 acc[4][8];
#pragma unroll
        for (int mi = 0; mi < 4; ++mi)
#pragma unroll
            for (int nj = 0; nj < 8; ++nj) acc[mi][nj] = (f32x4){0.f, 0.f, 0.f, 0.f};

        int4 pAh[2], pAl[2], pB[4];
        auto stageLoad = [&](int kt) {
#pragma unroll
            for (int it = 0; it < 2; ++it) {
                int idx = it * 256 + tid;
                int row = idx >> 2, kc = (idx & 3) << 3;
                int kg = kbase + kt + kc;
                if (XMODE && kg < kspl) {
                    int tok = tokens[row * Tz + t];
                    pAh[it] = *(const int4*)&emb[(size_t)tok * Ez + kg];
                    pAl[it] = make_int4(0, 0, 0, 0);
                } else {
                    size_t off = (size_t)row * ldah + (kg - kspl);
                    pAh[it] = *(const int4*)&Ah_hi[off];
                    pAl[it] = *(const int4*)&Ah_lo[off];
                }
            }
#pragma unroll
            for (int it = 0; it < 4; ++it) {
                int idx = it * 256 + tid;
                int n = idx >> 2, kc = (idx & 3) << 3;
                int kg = kbase + kt + kc;
                int colB = kg + ((kg < kspl) ? 0 : hoff);
                pB[it] = *(const int4*)&Bt[(size_t)(bn0 + n) * ldbt + colB];
            }
        };
        auto stageWrite = [&]() {
#pragma unroll
            for (int it = 0; it < 2; ++it) {
                int idx = it * 256 + tid;
                int row = idx >> 2, kc = (idx & 3) << 3;
                *(int4*)&Ahi[row * 40 + kc] = pAh[it];
                *(int4*)&Alo[row * 40 + kc] = pAl[it];
            }
#pragma unroll
            for (int it = 0; it < 4; ++it) {
                int idx = it * 256 + tid;
                int n = idx >> 2, kc = (idx & 3) << 3;
                *(int4*)&Bsh[n * 40 + kc] = pB[it];
            }
        };

        stageLoad(0);
        for (int kt = 0; kt < KCm; kt += 32) {
            stageWrite();
            __syncthreads();
            if (kt + 32 < KCm) stageLoad(kt + 32);
            bf16x8 bfr[8];
#pragma unroll
            for (int nj = 0; nj < 8; ++nj)
                bfr[nj] = *(const bf16x8*)&Bsh[(wc0 + nj * 16 + l15) * 40 + 8 * g];
#pragma unroll
            for (int mi = 0; mi < 4; ++mi) {
                int ar = (wr0 + mi * 16 + l15) * 40 + 8 * g;
                bf16x8 ah = *(const bf16x8*)&Ahi[ar];
                bf16x8 al = *(const bf16x8*)&Alo[ar];
#pragma unroll
                for (int nj = 0; nj < 8; ++nj) {
                    acc[mi][nj] = __builtin_amdgcn_mfma_f32_16x16x32_bf16(
                        ah, bfr[nj], acc[mi][nj], 0, 0, 0);
                    acc[mi][nj] = __builtin_amdgcn_mfma_f32_16x16x32_bf16(
                        al, bfr[nj], acc[mi][nj], 0, 0, 0);
                }
            }
            __syncthreads();
        }
        float* outp = parts + (size_t)z * 524288;
#pragma unroll
        for (int mi = 0; mi < 4; ++mi)
#pragma unroll
            for (int nj = 0; nj < 8; ++nj) {
                int col = bn0 + wc0 + nj * 16 + l15;
                int rowb = wr0 + mi * 16 + 4 * g;
#pragma unroll
                for (int r = 0; r < 4; ++r)
                    outp[(size_t)(rowb + r) * 4096 + col] = acc[mi][nj][r];
            }
        return;
    }
    // ---------------- VALU f32 fallback ----------------
    float* As = (float*)shraw;        // [16][68]
    float* Bsv = As + 16 * 68;        // [16][68]
    const int tx = tid & 15, ty = tid >> 4;
    const int bn0 = blockIdx.x * 64, bm0 = blockIdx.y * 64;
    const int kbase = blockIdx.z * KCv;
    const int ar = tid >> 2, ac4 = (tid & 3) << 2;
    const int bkk = tid >> 4, bn4 = (tid & 15) << 2;

    float acc[4][4];
#pragma unroll
    for (int i = 0; i < 4; i++)
#pragma unroll
        for (int j = 0; j < 4; j++) acc[i][j] = 0.f;

    float4 pa, pb;
    auto loadA = [&](int kt) {
        int kg = kbase + kt + ac4;
        if (XMODE && kg < kspl)
            pa = *(const float4*)(Axf + (size_t)(bm0 + ar) * Ez + kg);
        else
            pa = *(const float4*)(Ahf + (size_t)(bm0 + ar) * ldahf + (kg - kspl));
    };
    auto loadB = [&](int kt) {
        int kg = kbase + kt + bkk;
        int brow = kg + ((kg < kspl) ? 0 : hoff);
        int ng = bn0 + bn4;
        int pi = ng >> 10;
        const void* bptr = (pi == 0) ? B0 : (pi == 1) ? B1 : (pi == 2) ? B2 : B3;
        int col = ng & 1023;
        pb = *(const float4*)((const float*)bptr + (size_t)brow * ldb + col);
    };

    loadA(0); loadB(0);
    for (int kt = 0; kt < KCv; kt += 16) {
        As[(ac4 + 0) * 68 + ar] = pa.x; As[(ac4 + 1) * 68 + ar] = pa.y;
        As[(ac4 + 2) * 68 + ar] = pa.z; As[(ac4 + 3) * 68 + ar] = pa.w;
        *(float4*)&Bsv[bkk * 68 + bn4] = pb;
        __syncthreads();
        if (kt + 16 < KCv) { loadA(kt + 16); loadB(kt + 16); }
#pragma unroll
        for (int kk = 0; kk < 16; ++kk) {
            float a[4], b[4];
            *(float4*)&a[0] = *(const float4*)&As[kk * 68 + ty * 4];
            *(float4*)&b[0] = *(const float4*)&Bsv[kk * 68 + tx * 4];
#pragma unroll
            for (int i = 0; i < 4; ++i)
#pragma unroll
                for (int j = 0; j < 4; ++j)
                    acc[i][j] = fmaf(a[i], b[j], acc[i][j]);
        }
        __syncthreads();
    }
    float* out = parts + (size_t)blockIdx.z * 524288;
#pragma unroll
    for (int i = 0; i < 4; ++i)
#pragma unroll
        for (int j = 0; j < 4; ++j)
            out[(size_t)(bm0 + ty * 4 + i) * 4096 + bn0 + tx * 4 + j] = acc[i][j];
}

// =============================================================================
// Logits MFMA GEMM: out[b][t][v] = hs[3200,1024] @ Woutt^T + bout  (bf16 only)
// Grid (40, 25): 256-col x 128-row macro-tiles, same inner structure as rgemm.
// =============================================================================
__global__ __launch_bounds__(256, 2) void lgemm_k(
    const int* __restrict__ flag,
    const u16* __restrict__ hs_hi, const u16* __restrict__ hs_lo,
    const u16* __restrict__ Wt, const float* __restrict__ bout_f,
    float* __restrict__ out) {
    if (!*flag) return;
    __shared__ int4 shraw[2560];
    u16* Ahi = (u16*)shraw;
    u16* Alo = Ahi + 128 * 40;
    u16* Bsh = Alo + 128 * 40;
    const int tid = threadIdx.x;
    const int bn0 = blockIdx.x * 256, bm0 = blockIdx.y * 128;
    const int wid = tid >> 6, lane = tid & 63;
    const int l15 = lane & 15, g = lane >> 4;
    const int wr0 = (wid >> 1) * 64, wc0 = (wid & 1) * 128;

    f32x4 acc[4][8];
#pragma unroll
    for (int mi = 0; mi < 4; ++mi)
#pragma unroll
        for (int nj = 0; nj < 8; ++nj) acc[mi][nj] = (f32x4){0.f, 0.f, 0.f, 0.f};

    int4 pAh[2], pAl[2], pB[4];
    auto stageLoad = [&](int kt) {
#pragma unroll
        for (int it = 0; it < 2; ++it) {
            int idx = it * 256 + tid;
            int row = idx >> 2, kc = (idx & 3) << 3;
            size_t off = (size_t)(bm0 + row) * Hz + kt + kc;
            pAh[it] = *(const int4*)&hs_hi[off];
            pAl[it] = *(const int4*)&hs_lo[off];
        }
#pragma unroll
        for (int it = 0; it < 4; ++it) {
            int idx = it * 256 + tid;
            int n = idx >> 2, kc = (idx & 3) << 3;
            pB[it] = *(const int4*)&Wt[(size_t)(bn0 + n) * Hz + kt + kc];
        }
    };
    auto stageWrite = [&]() {
#pragma unroll
        for (int it = 0; it < 2; ++it) {
            int idx = it * 256 + tid;
            int row = idx >> 2, kc = (idx & 3) << 3;
            *(int4*)&Ahi[row * 40 + kc] = pAh[it];
            *(int4*)&Alo[row * 40 + kc] = pAl[it];
        }
#pragma unroll
        for (int it = 0; it < 4; ++it) {
            int idx = it * 256 + tid;
            int n = idx >> 2, kc = (idx & 3) << 3;
            *(int4*)&Bsh[n * 40 + kc] = pB[it];
        }
    };

    stageLoad(0);
    for (int kt = 0; kt < Hz; kt += 32) {
        stageWrite();
        __syncthreads();
        if (kt + 32 < Hz) stageLoad(kt + 32);
        bf16x8 bfr[8];
#pragma unroll
        for (int nj = 0; nj < 8; ++nj)
            bfr[nj] = *(const bf16x8*)&Bsh[(wc0 + nj * 16 + l15) * 40 + 8 * g];
#pragma unroll
        for (int mi = 0; mi < 4; ++mi) {
            int ar = (wr0 + mi * 16 + l15) * 40 + 8 * g;
            bf16x8 ah = *(const bf16x8*)&Ahi[ar];
            bf16x8 al = *(const bf16x8*)&Alo[ar];
#pragma unroll
            for (int nj = 0; nj < 8; ++nj) {
                acc[mi][nj] = __builtin_amdgcn_mfma_f32_16x16x32_bf16(
                    ah, bfr[nj], acc[mi][nj], 0, 0, 0);
                acc[mi][nj] = __builtin_amdgcn_mfma_f32_16x16x32_bf16(
                    al, bfr[nj], acc[mi][nj], 0, 0, 0);
            }
        }
        __syncthreads();
    }
#pragma unroll
    for (int mi = 0; mi < 4; ++mi)
#pragma unroll
        for (int nj = 0; nj < 8; ++nj) {
            int col = bn0 + wc0 + nj * 16 + l15;
            if (col < Vz) {
                float bv = bout_f[col];
                int rowb = bm0 + wr0 + mi * 16 + 4 * g;
#pragma unroll
                for (int r = 0; r < 4; ++r) {
                    int grow = rowb + r;
                    int tt = grow >> 7, bb = grow & 127;
                    out[((size_t)(bb * Tz + tt)) * Vz + col] = acc[mi][nj][r] + bv;
                }
            }
        }
}

// =============================================================================
// f32 fallback logits GEMM (VALU, 128x128 tiles) — runs only when !isbf.
// =============================================================================
__global__ __launch_bounds__(256) void vlogits_k(
    const float* __restrict__ A, int lda,
    const void* __restrict__ B0, int ldb,
    const float* __restrict__ addv,
    float* __restrict__ Cout, int N, int K,
    const int* __restrict__ flag) {
    if (*flag) return;
    __shared__ float As[16][132];
    __shared__ float Bs[16][132];
    const int tid = threadIdx.x;
    const int tx = tid & 15, ty = tid >> 4;
    const int bn0 = blockIdx.x * 128, bm0 = blockIdx.y * 128;
    const int ar = tid >> 2, ac4 = (tid & 3) << 2;
    const int bk = tid >> 5, bn4 = (tid & 31) << 2;

    float acc[2][2][4][4];
#pragma unroll
    for (int mh = 0; mh < 2; mh++)
#pragma unroll
        for (int nh = 0; nh < 2; nh++)
#pragma unroll
            for (int i = 0; i < 4; i++)
#pragma unroll
                for (int j = 0; j < 4; j++) acc[mh][nh][i][j] = 0.f;

    float4 pa[2], pb[2];
    auto loadA = [&](int kt) {
#pragma unroll
        for (int it = 0; it < 2; ++it)
            pa[it] = *(const float4*)(A + (size_t)(bm0 + ar + it * 64) * lda + kt + ac4);
    };
    auto loadB = [&](int kt) {
#pragma unroll
        for (int it = 0; it < 2; ++it) {
            int kk = bk + it * 8;
            int ng = bn0 + bn4;
            float4 v = {0.f, 0.f, 0.f, 0.f};
            if (ng < N)
                v = *(const float4*)((const float*)B0 + (size_t)(kt + kk) * ldb + ng);
            pb[it] = v;
        }
    };
    loadA(0); loadB(0);
    for (int kt = 0; kt < K; kt += 16) {
#pragma unroll
        for (int it = 0; it < 2; ++it) {
            int r = ar + it * 64;
            As[ac4 + 0][r] = pa[it].x; As[ac4 + 1][r] = pa[it].y;
            As[ac4 + 2][r] = pa[it].z; As[ac4 + 3][r] = pa[it].w;
            *(float4*)&Bs[bk + it * 8][bn4] = pb[it];
        }
        __syncthreads();
        if (kt + 16 < K) { loadA(kt + 16); loadB(kt + 16); }
#pragma unroll
        for (int kk = 0; kk < 16; ++kk) {
            float a[2][4], b[2][4];
            *(float4*)&a[0][0] = *(const float4*)&As[kk][ty * 4];
            *(float4*)&a[1][0] = *(const float4*)&As[kk][64 + ty * 4];
            *(float4*)&b[0][0] = *(const float4*)&Bs[kk][tx * 4];
            *(float4*)&b[1][0] = *(const float4*)&Bs[kk][64 + tx * 4];
#pragma unroll
            for (int mh = 0; mh < 2; ++mh)
#pragma unroll
                for (int i = 0; i < 4; ++i)
#pragma unroll
                    for (int nh = 0; nh < 2; ++nh)
#pragma unroll
                        for (int j = 0; j < 4; ++j)
                            acc[mh][nh][i][j] =
                                fmaf(a[mh][i], b[nh][j], acc[mh][nh][i][j]);
        }
        __syncthreads();
    }
#pragma unroll
    for (int mh = 0; mh < 2; ++mh)
#pragma unroll
        for (int i = 0; i < 4; ++i) {
            int grow = bm0 + mh * 64 + ty * 4 + i;
#pragma unroll
            for (int nh = 0; nh < 2; ++nh)
#pragma unroll
                for (int j = 0; j < 4; ++j) {
                    int gcol = bn0 + nh * 64 + tx * 4 + j;
                    if (gcol < N) {
                        float v = acc[mh][nh][i][j] + addv[gcol];
                        int tt = grow >> 7, bb = grow & 127;
                        Cout[((size_t)(bb * Tz + tt)) * Vz + gcol] = v;
                    }
                }
        }
}

extern "C" void kernel_launch(void* const* d_in, const int* in_sizes, int n_in,
                              void* d_out, int out_size, void* d_ws, size_t ws_size,
                              hipStream_t stream) {
    const int* tokens = (const int*)d_in[0];
    const void* features = d_in[1];    // [128,2048]
    const void* embedding = d_in[2];   // [10000,512]
    const void* Wp = d_in[3];          // [2048,1024]
    const void* bp = d_in[4];
    const void* W0[4] = {d_in[5], d_in[7], d_in[9], d_in[11]};   // each [2560,1024]
    const void* b0[4] = {d_in[6], d_in[8], d_in[10], d_in[12]};
    const void* W1[4] = {d_in[13], d_in[15], d_in[17], d_in[19]}; // each [2048,1024]
    const void* b1[4] = {d_in[14], d_in[16], d_in[18], d_in[20]};
    const void* Wout = d_in[21];       // [1024,10000]
    const void* bout = d_in[22];

    char* w = (char*)d_ws;
    size_t cur = 0;
    auto alloc = [&](size_t bytes) {
        size_t o = cur;
        cur += (bytes + 255) & ~(size_t)255;
        return o;
    };
    u16* W0t = (u16*)(w + alloc((size_t)4096 * 2560 * 2));     // 20.97 MB
    u16* W1t = (u16*)(w + alloc((size_t)4096 * 2048 * 2));     // 16.78 MB
    u16* Woutt = (u16*)(w + alloc((size_t)10240 * 1024 * 2));  // 20.97 MB (padded)
    u16* hs_hi = (u16*)(w + alloc((size_t)3200 * 1024 * 2));
    u16* hs_lo = (u16*)(w + alloc((size_t)3200 * 1024 * 2));
    float* parts = (float*)(w + alloc((size_t)4 * 128 * 4096 * 4));  // 8.39 MB
    float* Sfeat = (float*)(w + alloc((size_t)128 * 4096 * 4));
    float* featc = (float*)(w + alloc((size_t)Bz * Fz * 4));
    float* featf = (float*)(w + alloc((size_t)Bz * Hz * 4));
    u16* feat_hi = (u16*)(w + alloc((size_t)Bz * Hz * 2));
    u16* feat_lo = (u16*)(w + alloc((size_t)Bz * Hz * 2));
    // zeroed state block (contiguous)
    u16* h0_hi = (u16*)(w + alloc((size_t)Bz * Hz * 2));
    u16* h0_lo = (u16*)(w + alloc((size_t)Bz * Hz * 2));
    u16* comb1_hi = (u16*)(w + alloc((size_t)Bz * 2048 * 2));
    u16* comb1_lo = (u16*)(w + alloc((size_t)Bz * 2048 * 2));
    float* c0 = (float*)(w + alloc((size_t)Bz * Hz * 4));
    float* c1 = (float*)(w + alloc((size_t)Bz * Hz * 4));
    size_t stateBytes = (size_t)Bz * Hz * 2 * 2 + (size_t)Bz * 2048 * 2 * 2 +
                        (size_t)Bz * Hz * 4 * 2;
    float* bp_f = (float*)(w + alloc(1024 * 4));
    float* b0_f = (float*)(w + alloc(4096 * 4));
    float* b1_f = (float*)(w + alloc(4096 * 4));
    float* bout_f = (float*)(w + alloc((size_t)Vz * 4));
    int* dflag = (int*)(w + alloc(256));
    (void)ws_size; (void)in_sizes; (void)n_in; (void)out_size;

    // f32-fallback scratch ALIASED over W0t/W1t (mutually exclusive with bf16 path)
    float* X0f = (float*)W0t;                       // [3200][512]
    float* hsf = X0f + (size_t)3200 * 512;          // [3200][1024]
    float* h0f = hsf + (size_t)3200 * 1024;         // [128][1024]
    float* comb1f = h0f + (size_t)128 * 1024;       // [128][2048]

    // 0) dtype detect
    detect_k<<<1, 256, 0, stream>>>((const u16*)embedding, dflag);

    // 1) zero-init (BEFORE trans_k so bf16 path can overwrite the aliased region)
    hipMemsetAsync(Woutt, 0, (size_t)10240 * 1024 * 2, stream);        // incl. pad rows
    hipMemsetAsync(h0f, 0, (size_t)(128 * 1024 + 128 * 2048) * 4, stream);
    hipMemsetAsync(h0_hi, 0, stateBytes, stream);

    // 2) biases, features, f32 gather (fallback only)
    pack2_k<<<76, 256, 0, stream>>>(bp, b0[0], b0[1], b0[2], b0[3],
                                    b1[0], b1[1], b1[2], b1[3], bout,
                                    bp_f, b0_f, b1_f, bout_f, dflag);
    convf_k<<<1024, 256, 0, stream>>>(features, featc, Bz * Fz, dflag);
    gatherf_k<<<1600, 256, 0, stream>>>(tokens, embedding, X0f, dflag);

    // 3) weight transposes (bf16 path only; no-op otherwise)
    trans_k<<<dim3(32, 80, 4), 256, 0, stream>>>(
        (const u16*)W0[0], (const u16*)W0[1], (const u16*)W0[2], (const u16*)W0[3],
        2560, 1024, W0t, dflag);
    trans_k<<<dim3(32, 64, 4), 256, 0, stream>>>(
        (const u16*)W1[0], (const u16*)W1[1], (const u16*)W1[2], (const u16*)W1[3],
        2048, 1024, W1t, dflag);
    trans_k<<<dim3(313, 32, 1), 256, 0, stream>>>(
        (const u16*)Wout, (const u16*)Wout, (const u16*)Wout, (const u16*)Wout,
        1024, 10000, Woutt, dflag);

    // 4) feat = leaky_relu(featc @ Wp + bp)  (VALU, both dtypes) + bf16 split
    sgemm_part_k<false><<<dim3(16, 2, 4), 256, 0, stream>>>(
        featc, Fz, Wp, Wp, Wp, Wp, Hz, 0, parts, 1024, 512, dflag);
    sumPu_k<1, 1><<<512, 256, 0, stream>>>(parts, 10, bp_f, 0, 0,
                                           featf, feat_hi, feat_lo, Bz * Hz);

    // 5) Sfeat = feat @ W0[rows 512:1536] + b0
    rgemm_k<0><<<dim3(64, 2, 4), 256, 0, stream>>>(
        dflag, 0, nullptr, nullptr, feat_hi, feat_lo, 1024, 0, 512,
        W0t, 2560, 256, parts,
        nullptr, featf, 1024, W0[0], W0[1], W0[2], W0[3], 1024, 256);
    sumPu_k<0, 0><<<2048, 256, 0, stream>>>(parts, 12, b0_f, 0, 0,
                                            Sfeat, nullptr, nullptr, Bz * 4096);

    // 6) time loop
    for (int t = 0; t < Tz; t++) {
        // layer 0: [x_t | h0] @ W0[[0:512)+(1536:2560)]  (K = 1536, P = 4)
        rgemm_k<1><<<dim3(64, 2, 4), 256, 0, stream>>>(
            dflag, t, tokens, (const u16*)embedding, h0_hi, h0_lo, 1024, 512, 1024,
            W0t, 2560, 384, parts,
            X0f + (size_t)t * 128 * 512, h0f, 1024,
            W0[0], W0[1], W0[2], W0[3], 1024, 384);
        cellu_k<<<512, 256, 0, stream>>>(
            parts, Sfeat, 4096, 127, c0,
            h0_hi, h0_lo, h0f, 1024,
            comb1_hi, comb1_lo, comb1f, 2048, dflag);
        // layer 1: [h0n | h1] @ W1  (K = 2048, P = 4)
        rgemm_k<0><<<dim3(64, 2, 4), 256, 0, stream>>>(
            dflag, 0, nullptr, nullptr, comb1_hi, comb1_lo, 2048, 0, 0,
            W1t, 2048, 512, parts,
            nullptr, comb1f, 2048, W1[0], W1[1], W1[2], W1[3], 1024, 512);
        cellu_k<<<512, 256, 0, stream>>>(
            parts, b1_f, 0, 0, c1,
            hs_hi + (size_t)t * 128 * 1024, hs_lo + (size_t)t * 128 * 1024,
            hsf + (size_t)t * 128 * 1024, 1024,
            comb1_hi + 1024, comb1_lo + 1024, comb1f + 1024, 2048, dflag);
    }

    // 7) logits = hs @ Wout + bout -> out[b][t][v] f32
    lgemm_k<<<dim3(40, 25), 256, 0, stream>>>(dflag, hs_hi, hs_lo, Woutt, bout_f,
                                              (float*)d_out);
    vlogits_k<<<dim3(79, 25), 256, 0, stream>>>(hsf, Hz, Wout, Vz, bout_f,
                                                (float*)d_out, Vz, Hz, dflag);
}

// Round 4
// 2252.051 us; speedup vs baseline: 1.7768x; 1.7768x over previous
//
#include <hip/hip_runtime.h>
#include <hip/hip_bf16.h>
#include <cstdint>
#include <cstddef>

// Problem dims
constexpr int Bz = 128, Tz = 25, Ez = 512, Hz = 1024, Vz = 10000, Fz = 2048;

typedef unsigned short u16;
typedef __attribute__((ext_vector_type(8))) short bf16x8;   // 8 bf16 (4 VGPRs)
typedef __attribute__((ext_vector_type(4))) float f32x4;    // 4 f32 acc

__device__ __forceinline__ float sigm(float x) { return 1.f / (1.f + __expf(-x)); }
__device__ __forceinline__ float tanh_f(float x) {
    float e = __expf(-2.f * x);
    return 2.f / (1.f + e) - 1.f;
}
__device__ __forceinline__ float bf2f(u16 u) {
    return __builtin_bit_cast(float, ((unsigned)u) << 16);
}
__device__ __forceinline__ u16 f2bf(float x) {   // RNE
    unsigned u = __builtin_bit_cast(unsigned, x);
    u += 0x7fffu + ((u >> 16) & 1u);
    return (u16)(u >> 16);
}
__device__ __forceinline__ void splitbf(float x, u16& h, u16& l) {
    h = f2bf(x);
    l = f2bf(x - bf2f(h));
}

// ---------------- dtype detector (bf16=1 / f32=0), from embedding halfwords ----
__global__ __launch_bounds__(256) void detect_k(const u16* __restrict__ raw,
                                                int* __restrict__ flag) {
    __shared__ int sbuf[256];
    int tid = threadIdx.x, cnt = 0;
    for (int i = tid; i < 1024; i += 256) {
        u16 u = raw[2 * i];
        int e = (u >> 7) & 0xff;
        if (e >= 110 && e <= 127) cnt++;
    }
    sbuf[tid] = cnt;
    __syncthreads();
    for (int s = 128; s > 0; s >>= 1) {
        if (tid < s) sbuf[tid] += sbuf[tid + s];
        __syncthreads();
    }
    if (tid == 0) flag[0] = (sbuf[0] >= 512) ? 1 : 0;
}

__device__ __forceinline__ float ldf(const void* p, size_t i, int isbf) {
    return isbf ? bf2f(((const u16*)p)[i]) : ((const float*)p)[i];
}

// ---------------- features -> f32 ----------------
__global__ __launch_bounds__(256) void convf_k(const void* __restrict__ in,
                                               float* __restrict__ out, int n,
                                               const int* __restrict__ flag) {
    int idx = blockIdx.x * 256 + threadIdx.x;
    if (idx >= n) return;
    out[idx] = ldf(in, idx, *flag);
}

// ---------------- bias pack to f32 ----------------
__global__ __launch_bounds__(256) void pack2_k(
    const void* __restrict__ bp,
    const void* __restrict__ bf0, const void* __restrict__ bi0,
    const void* __restrict__ bo0, const void* __restrict__ bg0,
    const void* __restrict__ bf1, const void* __restrict__ bi1,
    const void* __restrict__ bo1, const void* __restrict__ bg1,
    const void* __restrict__ bout,
    float* __restrict__ bp_f, float* __restrict__ b0_f, float* __restrict__ b1_f,
    float* __restrict__ bout_f, const int* __restrict__ flag) {
    int idx = blockIdx.x * 256 + threadIdx.x;
    int isbf = *flag;
    if (idx < 1024) {
        bp_f[idx] = ldf(bp, idx, isbf);
    } else if (idx < 5120) {
        int n = idx - 1024, g = n >> 10, j = n & 1023;
        const void* s = (g == 0) ? bf0 : (g == 1) ? bi0 : (g == 2) ? bo0 : bg0;
        b0_f[n] = ldf(s, j, isbf);
    } else if (idx < 9216) {
        int n = idx - 5120, g = n >> 10, j = n & 1023;
        const void* s = (g == 0) ? bf1 : (g == 1) ? bi1 : (g == 2) ? bo1 : bg1;
        b1_f[n] = ldf(s, j, isbf);
    } else if (idx < 9216 + Vz) {
        int n = idx - 9216;
        bout_f[n] = ldf(bout, n, isbf);
    }
}

// ---------------- embedding gather + hi/lo split -> X0h/X0l [3200][512] --------
__global__ __launch_bounds__(256) void gsplit_k(const int* __restrict__ tok,
                                                const void* __restrict__ emb,
                                                u16* __restrict__ Xh,
                                                u16* __restrict__ Xl,
                                                const int* __restrict__ flag) {
    int idx = blockIdx.x * 256 + threadIdx.x;   // 3200*128
    if (idx >= 3200 * (Ez / 4)) return;
    int r = idx >> 7, c4 = (idx & 127) << 2;
    int t = r >> 7, b = r & 127;
    int tk = tok[b * Tz + t];
    int isbf = *flag;
    ushort4 h4, l4;
    float v0 = ldf(emb, (size_t)tk * Ez + c4 + 0, isbf);
    float v1 = ldf(emb, (size_t)tk * Ez + c4 + 1, isbf);
    float v2 = ldf(emb, (size_t)tk * Ez + c4 + 2, isbf);
    float v3 = ldf(emb, (size_t)tk * Ez + c4 + 3, isbf);
    splitbf(v0, h4.x, l4.x);
    splitbf(v1, h4.y, l4.y);
    splitbf(v2, h4.z, l4.z);
    splitbf(v3, h4.w, l4.w);
    *(ushort4*)&Xh[(size_t)r * Ez + c4] = h4;
    *(ushort4*)&Xl[(size_t)r * Ez + c4] = l4;
}

// ---------------- weight transpose + hi/lo split ------------------------------
// src W[K][Nsrc] (dtype via flag) -> Wh/Wl[(z*Nsrc + n)][K]   (n may exceed Nsrc
// for padded dsts: writes zeros). Grid (n_tiles, K/32, nmats).
__global__ __launch_bounds__(256) void wsplit_k(
    const void* __restrict__ s0, const void* __restrict__ s1,
    const void* __restrict__ s2, const void* __restrict__ s3,
    int K, int Nsrc, u16* __restrict__ Wh, u16* __restrict__ Wl,
    const int* __restrict__ flag) {
    int z = blockIdx.z;
    const void* src = (z == 0) ? s0 : (z == 1) ? s1 : (z == 2) ? s2 : s3;
    __shared__ float tb[32][33];
    int n0 = blockIdx.x * 32, k0 = blockIdx.y * 32, tid = threadIdx.x;
    int isbf = *flag;
    for (int i = 0; i < 4; i++) {
        int idx = i * 256 + tid, rr = idx >> 5, cc = idx & 31;
        int k = k0 + rr, n = n0 + cc;
        tb[rr][cc] = (n < Nsrc) ? ldf(src, (size_t)k * Nsrc + n, isbf) : 0.f;
    }
    __syncthreads();
    size_t dbase = (size_t)z * Nsrc;
    for (int i = 0; i < 4; i++) {
        int idx = i * 256 + tid, rr = idx >> 5, cc = idx & 31;
        int n = n0 + rr, k = k0 + cc;
        u16 hh, ll;
        splitbf(tb[cc][rr], hh, ll);
        size_t o = (dbase + n) * (size_t)K + k;
        Wh[o] = hh;
        Wl[o] = ll;
    }
}

// ---------------- LSTM cell elementwise, fused partial-sum --------------------
// parts: [P][128][4096]; add: Sfeat row (astride=4096,amask=127) or bias (0,0).
__global__ __launch_bounds__(256) void cellu_k(
    const float* __restrict__ parts, int P,
    const float* __restrict__ add, int astride, int amask,
    float* __restrict__ c,
    u16* __restrict__ hi1, u16* __restrict__ lo1, int ld1,
    u16* __restrict__ hi2, u16* __restrict__ lo2, int ld2) {
    int idx = blockIdx.x * 256 + threadIdx.x;   // 131072
    int m = idx >> 10, j = idx & 1023;
    size_t ab = (size_t)(m & amask) * astride;
    float gf = add[ab + j];
    float gi = add[ab + 1024 + j];
    float go = add[ab + 2048 + j];
    float gg = add[ab + 3072 + j];
    size_t base = (size_t)m * 4096 + j;
    for (int p = 0; p < P; ++p) {
        const float* pp = parts + (size_t)p * 524288 + base;
        gf += pp[0]; gi += pp[1024]; go += pp[2048]; gg += pp[3072];
    }
    float f = sigm(gf), ii = sigm(gi), o = sigm(go), g = tanh_f(gg);
    float cn = f * c[idx] + ii * g;
    c[idx] = cn;
    float h = o * tanh_f(cn);
    u16 hh, hl;
    splitbf(h, hh, hl);
    size_t o1 = (size_t)m * ld1 + j, o2 = (size_t)m * ld2 + j;
    hi1[o1] = hh; lo1[o1] = hl;
    hi2[o2] = hh; lo2[o2] = hl;
}

// ---------------- partial-sum reducer (+addv, leaky, optional bf16 split) ------
template <int ACT, int SPLIT>
__global__ __launch_bounds__(256) void sumPu_k(
    const float* __restrict__ parts, int P, int Ns,
    const float* __restrict__ addv, int astride, int amask,
    float* __restrict__ out, u16* __restrict__ ohi, u16* __restrict__ olo,
    int total) {
    int idx = blockIdx.x * 256 + threadIdx.x;
    if (idx >= total) return;
    int m = idx >> Ns, col = idx & ((1 << Ns) - 1);
    float v = addv[(size_t)(m & amask) * astride + col];
    for (int p = 0; p < P; ++p) v += parts[(size_t)p * total + idx];
    if (ACT == 1) v = (v > 0.f) ? v : 0.01f * v;
    out[idx] = v;
    if (SPLIT) {
        u16 hh, hl;
        splitbf(v, hh, hl);
        ohi[idx] = hh; olo[idx] = hl;
    }
}

// =============================================================================
// VALU f32 split-K GEMM for the feature projection (both dtypes).
// Cpart[z][128][N] = A[128, z-chunk] @ B[rows][N]  (B original layout, ldf)
// =============================================================================
__global__ __launch_bounds__(256) void sgemm_part_k(
    const float* __restrict__ A, int lda,
    const void* __restrict__ B0, int ldb,
    float* __restrict__ Cpart, int N, int KC,
    const int* __restrict__ flag) {
    __shared__ float As[16][68];
    __shared__ float Bs[16][68];
    const int tid = threadIdx.x;
    const int tx = tid & 15, ty = tid >> 4;
    const int bn0 = blockIdx.x * 64, bm0 = blockIdx.y * 64;
    const int kbase = blockIdx.z * KC;
    const int isbf = *flag;
    const int ar = tid >> 2, ac4 = (tid & 3) << 2;
    const int bkk = tid >> 4, bn4 = (tid & 15) << 2;

    float acc[4][4];
#pragma unroll
    for (int i = 0; i < 4; i++)
#pragma unroll
        for (int j = 0; j < 4; j++) acc[i][j] = 0.f;

    float4 pa, pb;
    auto loadA = [&](int kt) {
        pa = *(const float4*)(A + (size_t)(bm0 + ar) * lda + kbase + kt + ac4);
    };
    auto loadB = [&](int kt) {
        size_t off = (size_t)(kbase + kt + bkk) * ldb + bn0 + bn4;
        if (isbf) {
            const u16* us = (const u16*)B0 + off;
            pb.x = bf2f(us[0]); pb.y = bf2f(us[1]);
            pb.z = bf2f(us[2]); pb.w = bf2f(us[3]);
        } else {
            pb = *(const float4*)((const float*)B0 + off);
        }
    };

    loadA(0); loadB(0);
    for (int kt = 0; kt < KC; kt += 16) {
        As[ac4 + 0][ar] = pa.x; As[ac4 + 1][ar] = pa.y;
        As[ac4 + 2][ar] = pa.z; As[ac4 + 3][ar] = pa.w;
        *(float4*)&Bs[bkk][bn4] = pb;
        __syncthreads();
        if (kt + 16 < KC) { loadA(kt + 16); loadB(kt + 16); }
#pragma unroll
        for (int kk = 0; kk < 16; ++kk) {
            float a[4], b[4];
            *(float4*)&a[0] = *(const float4*)&As[kk][ty * 4];
            *(float4*)&b[0] = *(const float4*)&Bs[kk][tx * 4];
#pragma unroll
            for (int i = 0; i < 4; ++i)
#pragma unroll
                for (int j = 0; j < 4; ++j)
                    acc[i][j] = fmaf(a[i], b[j], acc[i][j]);
        }
        __syncthreads();
    }
    float* out = Cpart + (size_t)blockIdx.z * 128 * N;
#pragma unroll
    for (int i = 0; i < 4; ++i)
#pragma unroll
        for (int j = 0; j < 4; ++j)
            out[(size_t)(bm0 + ty * 4 + i) * N + bn0 + tx * 4 + j] = acc[i][j];
}

// =============================================================================
// Recurrent MFMA GEMM (bf16x3 from hi/lo splits) -> parts[z][128][4096].
// A = concat( X (XK cols, from Xh/Xl) , H (from Ah/Al) ), M=128.
// W in transposed layout Wh/Wl[n][K_w]: W col for global k = k (k<XK) else k+hoff
// (XK=0: always +hoff). Tile 128x64, BK=32, split-K z = gridDim.x/64.
// =============================================================================
template <int XK>
__global__ __launch_bounds__(256) void rgemm_k(
    const u16* __restrict__ Xh, const u16* __restrict__ Xl, int ldx,
    const u16* __restrict__ Ah, const u16* __restrict__ Al, int ldah,
    const u16* __restrict__ Wh, const u16* __restrict__ Wl, int ldk, int hoff,
    float* __restrict__ parts, int KC) {
    __shared__ u16 sh[15360];   // A hi/lo 128x40 each, B hi/lo 64x40 each
    u16* sAh = sh;
    u16* sAl = sh + 5120;
    u16* sBh = sh + 10240;
    u16* sBl = sh + 12800;
    const int tid = threadIdx.x;
    const int bid = blockIdx.x;
    const int bn0 = (bid & 63) * 64;
    const int z = bid >> 6;
    const int kbase = z * KC;
    const int wid = tid >> 6, lane = tid & 63;
    const int l15 = lane & 15, g = lane >> 4;
    const int wr0 = (wid >> 1) * 64, wc0 = (wid & 1) * 32;

    f32x4 acc[4][2];
#pragma unroll
    for (int mi = 0; mi < 4; ++mi)
#pragma unroll
        for (int nj = 0; nj < 2; ++nj) acc[mi][nj] = (f32x4){0.f, 0.f, 0.f, 0.f};

    int4 pAh[2], pAl[2], pBh, pBl;
    auto stageLoad = [&](int kt) {
#pragma unroll
        for (int it = 0; it < 2; ++it) {
            int idx = it * 256 + tid;
            int row = idx >> 2, kc = (idx & 3) << 3;
            int kg = kbase + kt + kc;
            if (XK > 0 && kg < XK) {
                size_t off = (size_t)row * ldx + kg;
                pAh[it] = *(const int4*)&Xh[off];
                pAl[it] = *(const int4*)&Xl[off];
            } else {
                size_t off = (size_t)row * ldah + (kg - XK);
                pAh[it] = *(const int4*)&Ah[off];
                pAl[it] = *(const int4*)&Al[off];
            }
        }
        {
            int n = tid >> 2, kc = (tid & 3) << 3;
            int kg = kbase + kt + kc;
            int colB = kg + ((XK > 0 && kg < XK) ? 0 : hoff);
            size_t wrow = (size_t)(bn0 + n) * ldk + colB;
            pBh = *(const int4*)&Wh[wrow];
            pBl = *(const int4*)&Wl[wrow];
        }
    };
    auto stageWrite = [&]() {
#pragma unroll
        for (int it = 0; it < 2; ++it) {
            int idx = it * 256 + tid;
            int row = idx >> 2, kc = (idx & 3) << 3;
            *(int4*)&sAh[row * 40 + kc] = pAh[it];
            *(int4*)&sAl[row * 40 + kc] = pAl[it];
        }
        int n = tid >> 2, kc = (tid & 3) << 3;
        *(int4*)&sBh[n * 40 + kc] = pBh;
        *(int4*)&sBl[n * 40 + kc] = pBl;
    };

    stageLoad(0);
    for (int kt = 0; kt < KC; kt += 32) {
        stageWrite();
        __syncthreads();
        if (kt + 32 < KC) stageLoad(kt + 32);
        bf16x8 bh[2], bl[2];
#pragma unroll
        for (int nj = 0; nj < 2; ++nj) {
            int co = (wc0 + nj * 16 + l15) * 40 + 8 * g;
            bh[nj] = *(const bf16x8*)&sBh[co];
            bl[nj] = *(const bf16x8*)&sBl[co];
        }
#pragma unroll
        for (int mi = 0; mi < 4; ++mi) {
            int ar = (wr0 + mi * 16 + l15) * 40 + 8 * g;
            bf16x8 ah = *(const bf16x8*)&sAh[ar];
            bf16x8 al = *(const bf16x8*)&sAl[ar];
#pragma unroll
            for (int nj = 0; nj < 2; ++nj) {
                acc[mi][nj] = __builtin_amdgcn_mfma_f32_16x16x32_bf16(
                    ah, bh[nj], acc[mi][nj], 0, 0, 0);
                acc[mi][nj] = __builtin_amdgcn_mfma_f32_16x16x32_bf16(
                    al, bh[nj], acc[mi][nj], 0, 0, 0);
                acc[mi][nj] = __builtin_amdgcn_mfma_f32_16x16x32_bf16(
                    ah, bl[nj], acc[mi][nj], 0, 0, 0);
            }
        }
        __syncthreads();
    }
    float* outp = parts + (size_t)z * 524288;
#pragma unroll
    for (int mi = 0; mi < 4; ++mi)
#pragma unroll
        for (int nj = 0; nj < 2; ++nj) {
            int col = bn0 + wc0 + nj * 16 + l15;
            int rowb = wr0 + mi * 16 + 4 * g;
#pragma unroll
            for (int r = 0; r < 4; ++r)
                outp[(size_t)(rowb + r) * 4096 + col] = acc[mi][nj][r];
        }
}

// =============================================================================
// Logits MFMA GEMM (bf16x3): out[b][t][v] = hs[3200,1024] @ WoutT + bout.
// Grid (40, 25): 256-col x 128-row macro-tiles, 4 waves of 64x128.
// =============================================================================
__global__ __launch_bounds__(256, 2) void lgemm_k(
    const u16* __restrict__ hs_hi, const u16* __restrict__ hs_lo,
    const u16* __restrict__ Wh, const u16* __restrict__ Wl,
    const float* __restrict__ bout_f, float* __restrict__ out) {
    __shared__ u16 sh[30720];   // A hi/lo 128x40, B hi/lo 256x40
    u16* sAh = sh;
    u16* sAl = sh + 5120;
    u16* sBh = sh + 10240;
    u16* sBl = sh + 20480;
    const int tid = threadIdx.x;
    const int bn0 = blockIdx.x * 256, bm0 = blockIdx.y * 128;
    const int wid = tid >> 6, lane = tid & 63;
    const int l15 = lane & 15, g = lane >> 4;
    const int wr0 = (wid >> 1) * 64, wc0 = (wid & 1) * 128;

    f32x4 acc[4][8];
#pragma unroll
    for (int mi = 0; mi < 4; ++mi)
#pragma unroll
        for (int nj = 0; nj < 8; ++nj) acc[mi][nj] = (f32x4){0.f, 0.f, 0.f, 0.f};

    int4 pAh[2], pAl[2], pBh[4], pBl[4];
    auto stageLoad = [&](int kt) {
#pragma unroll
        for (int it = 0; it < 2; ++it) {
            int idx = it * 256 + tid;
            int row = idx >> 2, kc = (idx & 3) << 3;
            size_t off = (size_t)(bm0 + row) * Hz + kt + kc;
            pAh[it] = *(const int4*)&hs_hi[off];
            pAl[it] = *(const int4*)&hs_lo[off];
        }
#pragma unroll
        for (int it = 0; it < 4; ++it) {
            int idx = it * 256 + tid;
            int n = idx >> 2, kc = (idx & 3) << 3;
            size_t wr = (size_t)(bn0 + n) * Hz + kt + kc;
            pBh[it] = *(const int4*)&Wh[wr];
            pBl[it] = *(const int4*)&Wl[wr];
        }
    };
    auto stageWrite = [&]() {
#pragma unroll
        for (int it = 0; it < 2; ++it) {
            int idx = it * 256 + tid;
            int row = idx >> 2, kc = (idx & 3) << 3;
            *(int4*)&sAh[row * 40 + kc] = pAh[it];
            *(int4*)&sAl[row * 40 + kc] = pAl[it];
        }
#pragma unroll
        for (int it = 0; it < 4; ++it) {
            int idx = it * 256 + tid;
            int n = idx >> 2, kc = (idx & 3) << 3;
            *(int4*)&sBh[n * 40 + kc] = pBh[it];
            *(int4*)&sBl[n * 40 + kc] = pBl[it];
        }
    };

    stageLoad(0);
    for (int kt = 0; kt < Hz; kt += 32) {
        stageWrite();
        __syncthreads();
        if (kt + 32 < Hz) stageLoad(kt + 32);
#pragma unroll
        for (int half = 0; half < 2; ++half) {
            bf16x8 bh[4], bl[4];
#pragma unroll
            for (int n2 = 0; n2 < 4; ++n2) {
                int co = (wc0 + (half * 4 + n2) * 16 + l15) * 40 + 8 * g;
                bh[n2] = *(const bf16x8*)&sBh[co];
                bl[n2] = *(const bf16x8*)&sBl[co];
            }
#pragma unroll
            for (int mi = 0; mi < 4; ++mi) {
                int ar = (wr0 + mi * 16 + l15) * 40 + 8 * g;
                bf16x8 ah = *(const bf16x8*)&sAh[ar];
                bf16x8 al = *(const bf16x8*)&sAl[ar];
#pragma unroll
                for (int n2 = 0; n2 < 4; ++n2) {
                    int j = half * 4 + n2;
                    acc[mi][j] = __builtin_amdgcn_mfma_f32_16x16x32_bf16(
                        ah, bh[n2], acc[mi][j], 0, 0, 0);
                    acc[mi][j] = __builtin_amdgcn_mfma_f32_16x16x32_bf16(
                        al, bh[n2], acc[mi][j], 0, 0, 0);
                    acc[mi][j] = __builtin_amdgcn_mfma_f32_16x16x32_bf16(
                        ah, bl[n2], acc[mi][j], 0, 0, 0);
                }
            }
        }
        __syncthreads();
    }
#pragma unroll
    for (int mi = 0; mi < 4; ++mi)
#pragma unroll
        for (int nj = 0; nj < 8; ++nj) {
            int col = bn0 + wc0 + nj * 16 + l15;
            if (col < Vz) {
                float bv = bout_f[col];
                int rowb = bm0 + wr0 + mi * 16 + 4 * g;
#pragma unroll
                for (int r = 0; r < 4; ++r) {
                    int grow = rowb + r;
                    int tt = grow >> 7, bb = grow & 127;
                    out[((size_t)(bb * Tz + tt)) * Vz + col] = acc[mi][nj][r] + bv;
                }
            }
        }
}

extern "C" void kernel_launch(void* const* d_in, const int* in_sizes, int n_in,
                              void* d_out, int out_size, void* d_ws, size_t ws_size,
                              hipStream_t stream) {
    const int* tokens = (const int*)d_in[0];
    const void* features = d_in[1];    // [128,2048]
    const void* embedding = d_in[2];   // [10000,512]
    const void* Wp = d_in[3];          // [2048,1024]
    const void* bp = d_in[4];
    const void* W0[4] = {d_in[5], d_in[7], d_in[9], d_in[11]};   // each [2560,1024]
    const void* b0[4] = {d_in[6], d_in[8], d_in[10], d_in[12]};
    const void* W1[4] = {d_in[13], d_in[15], d_in[17], d_in[19]}; // each [2048,1024]
    const void* b1[4] = {d_in[14], d_in[16], d_in[18], d_in[20]};
    const void* Wout = d_in[21];       // [1024,10000]
    const void* bout = d_in[22];

    char* w = (char*)d_ws;
    size_t cur = 0;
    auto alloc = [&](size_t bytes) {
        size_t o = cur;
        cur += (bytes + 255) & ~(size_t)255;
        return o;
    };
    u16* W0h = (u16*)(w + alloc((size_t)4096 * 2560 * 2));   // 20.97 MB
    u16* W0l = (u16*)(w + alloc((size_t)4096 * 2560 * 2));   // 20.97 MB
    u16* W1h = (u16*)(w + alloc((size_t)4096 * 2048 * 2));   // 16.78 MB
    u16* W1l = (u16*)(w + alloc((size_t)4096 * 2048 * 2));   // 16.78 MB
    u16* X0h = (u16*)(w + alloc((size_t)3200 * Ez * 2));     // 3.28 MB
    u16* X0l = (u16*)(w + alloc((size_t)3200 * Ez * 2));     // 3.28 MB
    u16* hs_hi = (u16*)(w + alloc((size_t)3200 * Hz * 2));   // 6.55 MB
    u16* hs_lo = (u16*)(w + alloc((size_t)3200 * Hz * 2));   // 6.55 MB
    float* parts = (float*)(w + alloc((size_t)8 * 524288 * 4)); // 16.78 MB
    float* Sfeat = (float*)(w + alloc((size_t)Bz * 4096 * 4));  // 2.10 MB
    float* featc = (float*)(w + alloc((size_t)Bz * Fz * 4));    // 1.05 MB
    float* featf = (float*)(w + alloc((size_t)Bz * Hz * 4));
    u16* feat_hi = (u16*)(w + alloc((size_t)Bz * Hz * 2));
    u16* feat_lo = (u16*)(w + alloc((size_t)Bz * Hz * 2));
    // zeroed state block (contiguous, all sizes multiples of 256)
    u16* h0_hi = (u16*)(w + alloc((size_t)Bz * Hz * 2));
    u16* h0_lo = (u16*)(w + alloc((size_t)Bz * Hz * 2));
    u16* comb1_hi = (u16*)(w + alloc((size_t)Bz * 2048 * 2));
    u16* comb1_lo = (u16*)(w + alloc((size_t)Bz * 2048 * 2));
    float* c0 = (float*)(w + alloc((size_t)Bz * Hz * 4));
    float* c1 = (float*)(w + alloc((size_t)Bz * Hz * 4));
    size_t stateBytes = (size_t)Bz * Hz * 2 * 2 + (size_t)Bz * 2048 * 2 * 2 +
                        (size_t)Bz * Hz * 4 * 2;
    float* bp_f = (float*)(w + alloc(1024 * 4));
    float* b0_f = (float*)(w + alloc(4096 * 4));
    float* b1_f = (float*)(w + alloc(4096 * 4));
    float* bout_f = (float*)(w + alloc((size_t)Vz * 4));
    int* dflag = (int*)(w + alloc(256));
    (void)ws_size; (void)in_sizes; (void)n_in; (void)out_size;

    // Wout transposed+split ALIASES W0h/W0l (built after the loop, 10240x1024 each
    // = exactly 20.97 MB <= W0h size).
    u16* Wouth = W0h;
    u16* Woutl = W0l;

    // 0) dtype detect
    detect_k<<<1, 256, 0, stream>>>((const u16*)embedding, dflag);

    // 1) zero states
    hipMemsetAsync(h0_hi, 0, stateBytes, stream);

    // 2) biases, features, embedding gather+split, weight transpose+split
    pack2_k<<<76, 256, 0, stream>>>(bp, b0[0], b0[1], b0[2], b0[3],
                                    b1[0], b1[1], b1[2], b1[3], bout,
                                    bp_f, b0_f, b1_f, bout_f, dflag);
    convf_k<<<1024, 256, 0, stream>>>(features, featc, Bz * Fz, dflag);
    gsplit_k<<<1600, 256, 0, stream>>>(tokens, embedding, X0h, X0l, dflag);
    wsplit_k<<<dim3(32, 80, 4), 256, 0, stream>>>(
        W0[0], W0[1], W0[2], W0[3], 2560, 1024, W0h, W0l, dflag);
    wsplit_k<<<dim3(32, 64, 4), 256, 0, stream>>>(
        W1[0], W1[1], W1[2], W1[3], 2048, 1024, W1h, W1l, dflag);

    // 3) feat = leaky_relu(featc @ Wp + bp)  (VALU f32, split-K P=4) + split
    sgemm_part_k<<<dim3(16, 2, 4), 256, 0, stream>>>(
        featc, Fz, Wp, Hz, parts, 1024, 512, dflag);
    sumPu_k<1, 1><<<512, 256, 0, stream>>>(parts, 4, 10, bp_f, 0, 0,
                                           featf, feat_hi, feat_lo, Bz * Hz);

    // 4) Sfeat = feat @ W0[rows 512:1536] + b0   (MFMA, z=8, KC=128)
    rgemm_k<0><<<512, 256, 0, stream>>>(
        nullptr, nullptr, 0, feat_hi, feat_lo, 1024,
        W0h, W0l, 2560, 512, parts, 128);
    sumPu_k<0, 0><<<2048, 256, 0, stream>>>(parts, 8, 12, b0_f, 0, 0,
                                            Sfeat, nullptr, nullptr, Bz * 4096);

    // 5) time loop (MFMA split-K z=8)
    for (int t = 0; t < Tz; t++) {
        // layer 0: [x_t | h0] @ W0[[0:512)+(1536:2560)]  K=1536, KC=192
        rgemm_k<512><<<512, 256, 0, stream>>>(
            X0h + (size_t)t * 128 * Ez, X0l + (size_t)t * 128 * Ez, Ez,
            h0_hi, h0_lo, 1024, W0h, W0l, 2560, 1024, parts, 192);
        cellu_k<<<512, 256, 0, stream>>>(
            parts, 8, Sfeat, 4096, 127, c0,
            h0_hi, h0_lo, 1024, comb1_hi, comb1_lo, 2048);
        // layer 1: [h0n | h1] @ W1  K=2048, KC=256
        rgemm_k<0><<<512, 256, 0, stream>>>(
            nullptr, nullptr, 0, comb1_hi, comb1_lo, 2048,
            W1h, W1l, 2048, 0, parts, 256);
        cellu_k<<<512, 256, 0, stream>>>(
            parts, 8, b1_f, 0, 0, c1,
            hs_hi + (size_t)t * 128 * Hz, hs_lo + (size_t)t * 128 * Hz, 1024,
            comb1_hi + 1024, comb1_lo + 1024, 2048);
    }

    // 6) Wout transpose+split into aliased region (after last W0 use)
    wsplit_k<<<dim3(320, 32, 1), 256, 0, stream>>>(
        Wout, Wout, Wout, Wout, 1024, Vz, Wouth, Woutl, dflag);

    // 7) logits (MFMA bf16x3) -> out[b][t][v] f32
    lgemm_k<<<dim3(40, 25), 256, 0, stream>>>(hs_hi, hs_lo, Wouth, Woutl,
                                              bout_f, (float*)d_out);
}